// Round 10
// baseline (4147.792 us; speedup 1.0000x reference)
//
#include <hip/hip_runtime.h>

#define LSEQ 50
#define BATCH 256
#define DIN 256
#define LAT 512
#define HID 1024
#define ROWSTRIDE 257  // D_IN + 1 (dt channel)
#define NBLK 256

typedef __attribute__((ext_vector_type(8))) short s16x8;
typedef __attribute__((ext_vector_type(4))) float f32x4;
using u16 = unsigned short;
using u64 = unsigned long long;

__device__ __forceinline__ u16 bfhi(float v) {
  union { float f; unsigned u; } a; a.f = v;
  return (u16)((a.u + 0x7FFFu + ((a.u >> 16) & 1u)) >> 16);
}
__device__ __forceinline__ void split2(float v, u16& h, u16& l) {
  u16 hu = bfhi(v);
  union { unsigned u; float f; } hf; hf.u = ((unsigned)hu) << 16;
  h = hu; l = bfhi(v - hf.f);
}
__device__ __forceinline__ float p2f(u16 h, u16 l) {
  union { unsigned u; float f; } a, b;
  a.u = ((unsigned)h) << 16; b.u = ((unsigned)l) << 16;
  return a.f + b.f;
}
__device__ __forceinline__ float sigmoidf_(float x) { return 1.f / (1.f + __expf(-x)); }
__device__ __forceinline__ f32x4 mfma16(s16x8 a, s16x8 b, f32x4 c) {
  return __builtin_amdgcn_mfma_f32_16x16x32_bf16(a, b, c, 0, 0, 0);
}
__device__ __forceinline__ f32x4 mfma3(s16x8 ah, s16x8 al, s16x8 bh, s16x8 bl, f32x4 c) {
  c = mfma16(ah, bh, c); c = mfma16(ah, bl, c); c = mfma16(al, bh, c); return c;
}
__device__ __forceinline__ ushort4 ldu4(const u16* p) { return *(const ushort4*)p; }
__device__ __forceinline__ void stu4(u16* p, ushort4 v) { *(ushort4*)p = v; }

// ---------- coherent (LLC-authoritative) accessors for cross-block state ----------
__device__ __forceinline__ ushort4 ldu4c(const u16* p) {
  u64 v = __hip_atomic_load((const u64*)p, __ATOMIC_RELAXED, __HIP_MEMORY_SCOPE_AGENT);
  union { u64 q; ushort4 s; } u; u.q = v; return u.s;
}
__device__ __forceinline__ u16 ldu16c(const u16* p) {
  return __hip_atomic_load(p, __ATOMIC_RELAXED, __HIP_MEMORY_SCOPE_AGENT);
}
__device__ __forceinline__ void stu16c(u16* p, u16 v) {
  __hip_atomic_store(p, v, __ATOMIC_RELAXED, __HIP_MEMORY_SCOPE_AGENT);
}

// ---------- in-phase barrier: LDS-ordered only ----------
__device__ __forceinline__ void kbar() {
  asm volatile("s_waitcnt lgkmcnt(0)" ::: "memory");
  __builtin_amdgcn_s_barrier();
}

// ---------- slice barrier, legacy (full vmcnt drain) ----------
__device__ __forceinline__ void slice_barrier(unsigned* line, unsigned k) {
  asm volatile("s_waitcnt vmcnt(0)" ::: "memory");
  __syncthreads();
  if (threadIdx.x == 0) {
    __hip_atomic_fetch_add(line, 1u, __ATOMIC_RELAXED, __HIP_MEMORY_SCOPE_AGENT);
    const unsigned tgt = k * 32u;
    while (__hip_atomic_load(line, __ATOMIC_RELAXED, __HIP_MEMORY_SCOPE_AGENT) < tgt) {
      __builtin_amdgcn_s_sleep(1);
    }
  }
  __syncthreads();
}

// ---------- slice barrier with overlapped prefetch ----------
// Caller issued exactly 12 prefetch loads AFTER its stores (with a compiler barrier
// between). vmcnt(12) retires in order -> all older stores complete; the 12 newest
// (weight prefetch) stay in flight across the barrier wait.
__device__ __forceinline__ void slice_barrier_p12(unsigned* line, unsigned k) {
  asm volatile("s_waitcnt vmcnt(12) lgkmcnt(0)" ::: "memory");
  __builtin_amdgcn_s_barrier();
  if (threadIdx.x == 0) {
    __hip_atomic_fetch_add(line, 1u, __ATOMIC_RELAXED, __HIP_MEMORY_SCOPE_AGENT);
    const unsigned tgt = k * 32u;
    while (__hip_atomic_load(line, __ATOMIC_RELAXED, __HIP_MEMORY_SCOPE_AGENT) < tgt) {
      __builtin_amdgcn_s_sleep(1);
    }
  }
  __builtin_amdgcn_s_barrier();
}

// ---------- preprocessing (unchanged) ----------
__global__ __launch_bounds__(256) void tsplit_k(const float* __restrict__ W,
    u16* __restrict__ Thi, u16* __restrict__ Tlo, int K, int N)
{
  __shared__ unsigned Ts[32][33];
  const int bk = blockIdx.x * 32, bn = blockIdx.y * 32;
  const int t = threadIdx.x;
  const int n_l = t & 31, k_l4 = (t >> 5) * 4;
  #pragma unroll
  for (int i = 0; i < 4; i++) {
    float v = W[(size_t)(bk + k_l4 + i) * N + bn + n_l];
    u16 h, l; split2(v, h, l);
    Ts[k_l4 + i][n_l] = ((unsigned)h << 16) | l;
  }
  __syncthreads();
  const int k_l = t & 31, n_l2 = t >> 5;
  #pragma unroll
  for (int i = 0; i < 4; i++) {
    int nn = n_l2 + 8 * i;
    unsigned u = Ts[k_l][nn];
    size_t o = (size_t)(bn + nn) * K + bk + k_l;
    Thi[o] = (u16)(u >> 16);
    Tlo[o] = (u16)(u & 0xFFFFu);
  }
}

__global__ __launch_bounds__(256) void esplit_k(const float* __restrict__ W,
    u16* __restrict__ Phi, u16* __restrict__ Plo)
{
  size_t i4 = ((size_t)blockIdx.x * 256 + threadIdx.x) * 4;
  float4 v = *(const float4*)&W[i4];
  u16 h[4], l[4];
  split2(v.x, h[0], l[0]); split2(v.y, h[1], l[1]);
  split2(v.z, h[2], l[2]); split2(v.w, h[3], l[3]);
  *(ushort4*)&Phi[i4] = make_ushort4(h[0], h[1], h[2], h[3]);
  *(ushort4*)&Plo[i4] = make_ushort4(l[0], l[1], l[2], l[3]);
}

__global__ __launch_bounds__(256) void init_k(u16* __restrict__ c0h, u16* __restrict__ c0l,
                                              unsigned* __restrict__ bar)
{
  size_t i4 = ((size_t)blockIdx.x * 256 + threadIdx.x) * 4;
  *(ushort4*)&c0h[i4] = make_ushort4(0, 0, 0, 0);
  *(ushort4*)&c0l[i4] = make_ushort4(0, 0, 0, 0);
  if (blockIdx.x == 0 && threadIdx.x < 16) bar[threadIdx.x * 64] = 0u;
}

// ---------- gemm phase: 2-deep register prefetch; seg0-B optionally preloaded ----------
template<int EPI, int NITER, bool PRE>
__device__ __forceinline__ void gemm_phase(
    u16* __restrict__ Sah, u16* __restrict__ Sal,
    u16* __restrict__ Sbh, u16* __restrict__ Sbl,
    const u16* __restrict__ Ahi, const u16* __restrict__ Alo, int ldA, int m0,
    const u16* __restrict__ Bhi, const u16* __restrict__ Blo, int ldB, int n0,
    const float* __restrict__ bias,
    u16* __restrict__ Ohi, u16* __restrict__ Olo,
    const float* __restrict__ data, int t, int tid,
    const ushort4* preBh, const ushort4* preBl)
{
  constexpr int NSEG = NITER / 4;
  const int lane = tid & 63, wave = tid >> 6;
  const int wm = (wave >> 1) << 4, wn = (wave & 1) << 4;
  const int lr = lane & 15, lq = lane >> 4;
  const int srow = tid >> 3, sk4 = (tid & 7) << 2;
  const int sidx = srow * 40 + sk4;
  const size_t rowA = (size_t)(m0 + srow) * ldA + sk4;
  const size_t rowB = (size_t)(n0 + srow) * ldB + sk4;
  const int fa = (wm + lr) * 40 + lq * 8;
  const int fb = (wn + lr) * 40 + lq * 8;
  f32x4 acc0 = {0,0,0,0}, acc1 = {0,0,0,0};

  ushort4 ah0[4], al0[4], bh0[4], bl0[4];
  ushort4 ah1[4], al1[4], bh1[4], bl1[4];

  auto load0 = [&](int seg) {
    #pragma unroll
    for (int d = 0; d < 4; ++d) {
      const int k0 = (seg * 4 + d) << 5;
      ah0[d] = ldu4c(&Ahi[rowA + k0]); al0[d] = ldu4c(&Alo[rowA + k0]);
      bh0[d] = ldu4(&Bhi[rowB + k0]);  bl0[d] = ldu4(&Blo[rowB + k0]);
    }
  };
  auto load1 = [&](int seg) {
    #pragma unroll
    for (int d = 0; d < 4; ++d) {
      const int k0 = (seg * 4 + d) << 5;
      ah1[d] = ldu4c(&Ahi[rowA + k0]); al1[d] = ldu4c(&Alo[rowA + k0]);
      bh1[d] = ldu4(&Bhi[rowB + k0]);  bl1[d] = ldu4(&Blo[rowB + k0]);
    }
  };
  auto write0 = [&]() {
    #pragma unroll
    for (int d = 0; d < 4; ++d) {
      stu4(&Sah[d * 1280 + sidx], ah0[d]); stu4(&Sal[d * 1280 + sidx], al0[d]);
      stu4(&Sbh[d * 1280 + sidx], bh0[d]); stu4(&Sbl[d * 1280 + sidx], bl0[d]);
    }
  };
  auto write1 = [&]() {
    #pragma unroll
    for (int d = 0; d < 4; ++d) {
      stu4(&Sah[5120 + d * 1280 + sidx], ah1[d]); stu4(&Sal[5120 + d * 1280 + sidx], al1[d]);
      stu4(&Sbh[5120 + d * 1280 + sidx], bh1[d]); stu4(&Sbl[5120 + d * 1280 + sidx], bl1[d]);
    }
  };
  auto compute = [&](int g) {
    #pragma unroll
    for (int d = 0; d < 4; ++d) {
      const int o = g * 5120 + d * 1280;
      s16x8 ah = *(const s16x8*)&Sah[o + fa];
      s16x8 al = *(const s16x8*)&Sal[o + fa];
      s16x8 bh = *(const s16x8*)&Sbh[o + fb];
      s16x8 bl = *(const s16x8*)&Sbl[o + fb];
      if (d & 1) acc1 = mfma3(ah, al, bh, bl, acc1);
      else       acc0 = mfma3(ah, al, bh, bl, acc0);
    }
  };

  // prologue
  if constexpr (PRE) {
    #pragma unroll
    for (int d = 0; d < 4; ++d) {
      const int k0 = d << 5;
      ah0[d] = ldu4c(&Ahi[rowA + k0]); al0[d] = ldu4c(&Alo[rowA + k0]);
      bh0[d] = preBh[d]; bl0[d] = preBl[d];   // weights preloaded across the barrier
    }
  } else {
    load0(0);
  }
  load1(1);
  write0();
  kbar();
  for (int p = 0; p < NSEG; p += 2) {
    if (p + 2 < NSEG) load0(p + 2);
    compute(0);
    write1();
    kbar();
    if (p + 3 < NSEG) load1(p + 3);
    compute(1);
    if (p + 2 < NSEG) write0();
    kbar();
  }

  #pragma unroll
  for (int r = 0; r < 4; ++r) {
    const int row = m0 + wm + lq * 4 + r;
    const int col = n0 + wn + lr;
    float v = acc0[r] + acc1[r] + bias[col];
    size_t o = (size_t)row * HID + col;
    if (EPI == 1) {
      float h1 = tanhf(v);
      u16 h, l; split2(h1, h, l);
      stu16c(&Ohi[o], h); stu16c(&Olo[o], l);
    } else {
      float dt3 = data[(size_t)(t * BATCH + row) * ROWSTRIDE + DIN] * (1.f / 3.f);
      float y = p2f(ldu16c(&Ohi[o]), ldu16c(&Olo[o])) + v * dt3;
      u16 h, l; split2(y, h, l);
      stu16c(&Ohi[o], h); stu16c(&Olo[o], l);
    }
  }
}

// ---------- fused GRU phase: 2-deep pipeline; gh seg0-B preloaded when PLANES ----------
template<bool PLANES>
__device__ __forceinline__ void gru_phase(
    u16* pool,
    const u16* __restrict__ chi, const u16* __restrict__ clo,
    const float* __restrict__ whh, const u16* __restrict__ whhh, const u16* __restrict__ whhl,
    const float* __restrict__ wih, const u16* __restrict__ wihh, const u16* __restrict__ wihl,
    const float* __restrict__ bih, const float* __restrict__ bhh,
    const float* __restrict__ data, int t,
    u16* __restrict__ nhi, u16* __restrict__ nlo,
    float* __restrict__ out, int gc0, int m0, int tid,
    const ushort4* preBh, const ushort4* preBl)
{
  u16* sAh = pool;
  u16* sAl = pool + 5120;
  u16* sBh = pool + 10240;
  u16* sBl = pool + 25600;
  const int lane = tid & 63, wave = tid >> 6;
  const int wm = (wave >> 1) << 4, wn = (wave & 1) << 4;
  const int lr = lane & 15, lq = lane >> 4;
  const int srow = tid >> 3, sk4 = (tid & 7) << 2;
  const int sidx = srow * 40 + sk4;
  const int fa = (wm + lr) * 40 + lq * 8;
  const int fbn = (wn + lr) * 40 + lq * 8;
  f32x4 aR0 = {0,0,0,0}, aR1 = {0,0,0,0};
  f32x4 aZ0 = {0,0,0,0}, aZ1 = {0,0,0,0};
  f32x4 aNh0 = {0,0,0,0}, aNh1 = {0,0,0,0};
  f32x4 aNi0 = {0,0,0,0}, aNi1 = {0,0,0,0};

  // ===== gh: K=1024 over (chi | whh), 32 tiles = 16 segments of 2 =====
  {
    const size_t rowA = (size_t)(m0 + srow) * HID + sk4;
    const size_t rB0 = (size_t)(0 * 1024 + gc0 + srow) * 1024 + sk4;
    const size_t rB1 = (size_t)(1 * 1024 + gc0 + srow) * 1024 + sk4;
    const size_t rB2 = (size_t)(2 * 1024 + gc0 + srow) * 1024 + sk4;
    ushort4 Ah0[2], Al0[2], Bh0[2][3], Bl0[2][3];
    ushort4 Ah1[2], Al1[2], Bh1[2][3], Bl1[2][3];
    float4  F0[2][3], F1[2][3];

    auto load0 = [&](int seg) {
      #pragma unroll
      for (int j = 0; j < 2; ++j) {
        const int k0 = (seg * 2 + j) << 5;
        Ah0[j] = ldu4c(&chi[rowA + k0]); Al0[j] = ldu4c(&clo[rowA + k0]);
        if (PLANES) {
          Bh0[j][0] = ldu4(&whhh[rB0 + k0]); Bl0[j][0] = ldu4(&whhl[rB0 + k0]);
          Bh0[j][1] = ldu4(&whhh[rB1 + k0]); Bl0[j][1] = ldu4(&whhl[rB1 + k0]);
          Bh0[j][2] = ldu4(&whhh[rB2 + k0]); Bl0[j][2] = ldu4(&whhl[rB2 + k0]);
        } else {
          F0[j][0] = *(const float4*)&whh[rB0 + k0];
          F0[j][1] = *(const float4*)&whh[rB1 + k0];
          F0[j][2] = *(const float4*)&whh[rB2 + k0];
        }
      }
    };
    auto load1 = [&](int seg) {
      #pragma unroll
      for (int j = 0; j < 2; ++j) {
        const int k0 = (seg * 2 + j) << 5;
        Ah1[j] = ldu4c(&chi[rowA + k0]); Al1[j] = ldu4c(&clo[rowA + k0]);
        if (PLANES) {
          Bh1[j][0] = ldu4(&whhh[rB0 + k0]); Bl1[j][0] = ldu4(&whhl[rB0 + k0]);
          Bh1[j][1] = ldu4(&whhh[rB1 + k0]); Bl1[j][1] = ldu4(&whhl[rB1 + k0]);
          Bh1[j][2] = ldu4(&whhh[rB2 + k0]); Bl1[j][2] = ldu4(&whhl[rB2 + k0]);
        } else {
          F1[j][0] = *(const float4*)&whh[rB0 + k0];
          F1[j][1] = *(const float4*)&whh[rB1 + k0];
          F1[j][2] = *(const float4*)&whh[rB2 + k0];
        }
      }
    };
    auto write0 = [&]() {
      #pragma unroll
      for (int j = 0; j < 2; ++j) {
        stu4(&sAh[j * 1280 + sidx], Ah0[j]); stu4(&sAl[j * 1280 + sidx], Al0[j]);
        #pragma unroll
        for (int g = 0; g < 3; ++g) {
          if (PLANES) {
            stu4(&sBh[j * 3840 + g * 1280 + sidx], Bh0[j][g]);
            stu4(&sBl[j * 3840 + g * 1280 + sidx], Bl0[j][g]);
          } else {
            float4 w4 = F0[j][g];
            u16 h0,l0,h1,l1,h2,l2,h3,l3;
            split2(w4.x,h0,l0); split2(w4.y,h1,l1); split2(w4.z,h2,l2); split2(w4.w,h3,l3);
            stu4(&sBh[j * 3840 + g * 1280 + sidx], make_ushort4(h0,h1,h2,h3));
            stu4(&sBl[j * 3840 + g * 1280 + sidx], make_ushort4(l0,l1,l2,l3));
          }
        }
      }
    };
    auto write1 = [&]() {
      #pragma unroll
      for (int j = 0; j < 2; ++j) {
        stu4(&sAh[(2 + j) * 1280 + sidx], Ah1[j]); stu4(&sAl[(2 + j) * 1280 + sidx], Al1[j]);
        #pragma unroll
        for (int g = 0; g < 3; ++g) {
          if (PLANES) {
            stu4(&sBh[(2 + j) * 3840 + g * 1280 + sidx], Bh1[j][g]);
            stu4(&sBl[(2 + j) * 3840 + g * 1280 + sidx], Bl1[j][g]);
          } else {
            float4 w4 = F1[j][g];
            u16 h0,l0,h1,l1,h2,l2,h3,l3;
            split2(w4.x,h0,l0); split2(w4.y,h1,l1); split2(w4.z,h2,l2); split2(w4.w,h3,l3);
            stu4(&sBh[(2 + j) * 3840 + g * 1280 + sidx], make_ushort4(h0,h1,h2,h3));
            stu4(&sBl[(2 + j) * 3840 + g * 1280 + sidx], make_ushort4(l0,l1,l2,l3));
          }
        }
      }
    };
    auto compute = [&](int grp) {
      #pragma unroll
      for (int j = 0; j < 2; ++j) {
        const int slot = grp * 2 + j;
        const int sa = slot * 1280 + fa;
        const int sb = slot * 3840 + fbn;
        s16x8 ah = *(const s16x8*)&sAh[sa];
        s16x8 al = *(const s16x8*)&sAl[sa];
        #pragma unroll
        for (int g = 0; g < 3; ++g) {
          s16x8 bh = *(const s16x8*)&sBh[sb + g * 1280];
          s16x8 bl = *(const s16x8*)&sBl[sb + g * 1280];
          if (j) {
            if (g == 0) aR1 = mfma3(ah, al, bh, bl, aR1);
            else if (g == 1) aZ1 = mfma3(ah, al, bh, bl, aZ1);
            else aNh1 = mfma3(ah, al, bh, bl, aNh1);
          } else {
            if (g == 0) aR0 = mfma3(ah, al, bh, bl, aR0);
            else if (g == 1) aZ0 = mfma3(ah, al, bh, bl, aZ0);
            else aNh0 = mfma3(ah, al, bh, bl, aNh0);
          }
        }
      }
    };

    // prologue: seg0-B from prefetch regs (PLANES), A loaded here
    if constexpr (PLANES) {
      #pragma unroll
      for (int j = 0; j < 2; ++j) {
        const int k0 = j << 5;
        Ah0[j] = ldu4c(&chi[rowA + k0]); Al0[j] = ldu4c(&clo[rowA + k0]);
        #pragma unroll
        for (int g = 0; g < 3; ++g) { Bh0[j][g] = preBh[j * 3 + g]; Bl0[j][g] = preBl[j * 3 + g]; }
      }
    } else {
      load0(0);
    }
    load1(1); write0(); kbar();
    for (int p = 0; p < 16; p += 2) {
      if (p + 2 < 16) load0(p + 2);
      compute(0);
      write1();
      kbar();
      if (p + 3 < 16) load1(p + 3);
      compute(1);
      if (p + 2 < 16) write0();
      kbar();
    }
  }

  // ===== gi: K=256 over (x_t | wih), 8 tiles = 4 segments of 2 =====
  {
    const size_t rowX = (size_t)(t * BATCH + m0 + srow) * ROWSTRIDE + sk4;
    const size_t rB0 = (size_t)(0 * 1024 + gc0 + srow) * 256 + sk4;
    const size_t rB1 = (size_t)(1 * 1024 + gc0 + srow) * 256 + sk4;
    const size_t rB2 = (size_t)(2 * 1024 + gc0 + srow) * 256 + sk4;
    float4  X0[2], X1[2];
    ushort4 Bh0[2][3], Bl0[2][3], Bh1[2][3], Bl1[2][3];
    float4  F0[2][3], F1[2][3];

    auto load0 = [&](int seg) {
      #pragma unroll
      for (int j = 0; j < 2; ++j) {
        const int k0 = (seg * 2 + j) << 5;
        X0[j] = *(const float4*)&data[rowX + k0];
        if (PLANES) {
          Bh0[j][0] = ldu4(&wihh[rB0 + k0]); Bl0[j][0] = ldu4(&wihl[rB0 + k0]);
          Bh0[j][1] = ldu4(&wihh[rB1 + k0]); Bl0[j][1] = ldu4(&wihl[rB1 + k0]);
          Bh0[j][2] = ldu4(&wihh[rB2 + k0]); Bl0[j][2] = ldu4(&wihl[rB2 + k0]);
        } else {
          F0[j][0] = *(const float4*)&wih[rB0 + k0];
          F0[j][1] = *(const float4*)&wih[rB1 + k0];
          F0[j][2] = *(const float4*)&wih[rB2 + k0];
        }
      }
    };
    auto load1 = [&](int seg) {
      #pragma unroll
      for (int j = 0; j < 2; ++j) {
        const int k0 = (seg * 2 + j) << 5;
        X1[j] = *(const float4*)&data[rowX + k0];
        if (PLANES) {
          Bh1[j][0] = ldu4(&wihh[rB0 + k0]); Bl1[j][0] = ldu4(&wihl[rB0 + k0]);
          Bh1[j][1] = ldu4(&wihh[rB1 + k0]); Bl1[j][1] = ldu4(&wihl[rB1 + k0]);
          Bh1[j][2] = ldu4(&wihh[rB2 + k0]); Bl1[j][2] = ldu4(&wihl[rB2 + k0]);
        } else {
          F1[j][0] = *(const float4*)&wih[rB0 + k0];
          F1[j][1] = *(const float4*)&wih[rB1 + k0];
          F1[j][2] = *(const float4*)&wih[rB2 + k0];
        }
      }
    };
    auto writeX = [&](const float4* X, int base) {
      #pragma unroll
      for (int j = 0; j < 2; ++j) {
        u16 xh[4], xl[4];
        split2(X[j].x, xh[0], xl[0]); split2(X[j].y, xh[1], xl[1]);
        split2(X[j].z, xh[2], xl[2]); split2(X[j].w, xh[3], xl[3]);
        stu4(&sAh[(base + j) * 1280 + sidx], make_ushort4(xh[0], xh[1], xh[2], xh[3]));
        stu4(&sAl[(base + j) * 1280 + sidx], make_ushort4(xl[0], xl[1], xl[2], xl[3]));
      }
    };
    auto write0 = [&]() {
      writeX(X0, 0);
      #pragma unroll
      for (int j = 0; j < 2; ++j)
        #pragma unroll
        for (int g = 0; g < 3; ++g) {
          if (PLANES) {
            stu4(&sBh[j * 3840 + g * 1280 + sidx], Bh0[j][g]);
            stu4(&sBl[j * 3840 + g * 1280 + sidx], Bl0[j][g]);
          } else {
            float4 w4 = F0[j][g];
            u16 h0,l0,h1,l1,h2,l2,h3,l3;
            split2(w4.x,h0,l0); split2(w4.y,h1,l1); split2(w4.z,h2,l2); split2(w4.w,h3,l3);
            stu4(&sBh[j * 3840 + g * 1280 + sidx], make_ushort4(h0,h1,h2,h3));
            stu4(&sBl[j * 3840 + g * 1280 + sidx], make_ushort4(l0,l1,l2,l3));
          }
        }
    };
    auto write1 = [&]() {
      writeX(X1, 2);
      #pragma unroll
      for (int j = 0; j < 2; ++j)
        #pragma unroll
        for (int g = 0; g < 3; ++g) {
          if (PLANES) {
            stu4(&sBh[(2 + j) * 3840 + g * 1280 + sidx], Bh1[j][g]);
            stu4(&sBl[(2 + j) * 3840 + g * 1280 + sidx], Bl1[j][g]);
          } else {
            float4 w4 = F1[j][g];
            u16 h0,l0,h1,l1,h2,l2,h3,l3;
            split2(w4.x,h0,l0); split2(w4.y,h1,l1); split2(w4.z,h2,l2); split2(w4.w,h3,l3);
            stu4(&sBh[(2 + j) * 3840 + g * 1280 + sidx], make_ushort4(h0,h1,h2,h3));
            stu4(&sBl[(2 + j) * 3840 + g * 1280 + sidx], make_ushort4(l0,l1,l2,l3));
          }
        }
    };
    auto compute = [&](int grp) {
      #pragma unroll
      for (int j = 0; j < 2; ++j) {
        const int slot = grp * 2 + j;
        const int sa = slot * 1280 + fa;
        const int sb = slot * 3840 + fbn;
        s16x8 ah = *(const s16x8*)&sAh[sa];
        s16x8 al = *(const s16x8*)&sAl[sa];
        #pragma unroll
        for (int g = 0; g < 3; ++g) {
          s16x8 bh = *(const s16x8*)&sBh[sb + g * 1280];
          s16x8 bl = *(const s16x8*)&sBl[sb + g * 1280];
          if (j) {
            if (g == 0) aR1 = mfma3(ah, al, bh, bl, aR1);
            else if (g == 1) aZ1 = mfma3(ah, al, bh, bl, aZ1);
            else aNi1 = mfma3(ah, al, bh, bl, aNi1);
          } else {
            if (g == 0) aR0 = mfma3(ah, al, bh, bl, aR0);
            else if (g == 1) aZ0 = mfma3(ah, al, bh, bl, aZ0);
            else aNi0 = mfma3(ah, al, bh, bl, aNi0);
          }
        }
      }
    };

    load0(0); load1(1); write0(); kbar();
    for (int p = 0; p < 4; p += 2) {
      if (p + 2 < 4) load0(p + 2);
      compute(0);
      write1();
      kbar();
      if (p + 3 < 4) load1(p + 3);
      compute(1);
      if (p + 2 < 4) write0();
      kbar();
    }
  }

  const f32x4 aR = aR0 + aR1, aZ = aZ0 + aZ1, aNh = aNh0 + aNh1, aNi = aNi0 + aNi1;

  // ===== epilogue =====
  #pragma unroll
  for (int r = 0; r < 4; ++r) {
    const int row = m0 + wm + lq * 4 + r;
    const int jg = gc0 + wn + lr;
    float rr = sigmoidf_(aR[r] + bih[jg] + bhh[jg]);
    float zz = sigmoidf_(aZ[r] + bih[1024 + jg] + bhh[1024 + jg]);
    float nn = tanhf(aNi[r] + bih[2048 + jg] + rr * (aNh[r] + bhh[2048 + jg]));
    size_t oh = (size_t)row * HID + jg;
    float hv = p2f(ldu16c(&chi[oh]), ldu16c(&clo[oh]));
    float val = (1.f - zz) * nn + zz * hv;
    out[(size_t)LSEQ * BATCH * LAT + oh] = val;        // output 1 (new_h)
    if (jg < LAT) {
      out[((size_t)t * BATCH + row) * LAT + jg] = val; // output 0
      u16 h, l; split2(val, h, l);
      stu16c(&nhi[oh], h); stu16c(&nhi[oh + LAT], h);
      stu16c(&nlo[oh], l); stu16c(&nlo[oh + LAT], l);
    }
  }
}

// ---------- one persistent kernel, 8 independent batch-row slices ----------
template<bool PLANES>
__global__ __launch_bounds__(256) void fused_seq_k(
    const u16* __restrict__ w1h, const u16* __restrict__ w1l,
    const u16* __restrict__ w2h, const u16* __restrict__ w2l,
    const float* __restrict__ b1, const float* __restrict__ b2,
    u16* __restrict__ c0h, u16* __restrict__ c0l,
    u16* __restrict__ c1h, u16* __restrict__ c1l,
    u16* __restrict__ h1h, u16* __restrict__ h1l,
    const float* __restrict__ whh, const u16* __restrict__ whhh, const u16* __restrict__ whhl,
    const float* __restrict__ wih, const u16* __restrict__ wihh, const u16* __restrict__ wihl,
    const float* __restrict__ bih, const float* __restrict__ bhh,
    const float* __restrict__ data, float* __restrict__ out,
    unsigned* __restrict__ bar)
{
  __shared__ u16 pool[40960];   // 80 KB
  const int b = blockIdx.x;
  const int tid = threadIdx.x;
  const int slice = b >> 5;
  const int l = b & 31;
  const int m0 = slice << 5;
  unsigned* line = bar + slice * 64;
  unsigned rnd = 0;

  u16* Sah = pool;
  u16* Sal = pool + 10240;
  u16* Sbh = pool + 20480;
  u16* Sbl = pool + 30720;

  const int srow = tid >> 3, sk4 = (tid & 7) << 2;
  ushort4 preh[6], prel[6];

  auto pre_w = [&](const u16* Bh, const u16* Bl, int ldB, int n0) {   // 12 loads exactly
    size_t rowB = (size_t)(n0 + srow) * ldB + sk4;
    #pragma unroll
    for (int d = 0; d < 4; ++d) {
      preh[d] = ldu4(&Bh[rowB + (d << 5)]); prel[d] = ldu4(&Bl[rowB + (d << 5)]);
    }
    preh[4] = ldu4(&Bh[rowB]); prel[4] = ldu4(&Bl[rowB]);   // pad to 12 loads
    preh[5] = ldu4(&Bh[rowB]); prel[5] = ldu4(&Bl[rowB]);
  };
  auto pre_g = [&]() {   // 12 loads exactly (gh seg0: 2 tiles x 3 gates)
    const int gc0 = l << 5;
    #pragma unroll
    for (int j = 0; j < 2; ++j)
      #pragma unroll
      for (int g = 0; g < 3; ++g) {
        size_t rr = (size_t)(g * 1024 + gc0 + srow) * 1024 + (j << 5) + sk4;
        preh[j * 3 + g] = ldu4(&whhh[rr]); prel[j * 3 + g] = ldu4(&whhl[rr]);
      }
  };

  if constexpr (PLANES) {
    pre_w(w1h, w1l, 512, l << 5);   // initial prefetch for (t=0, s=0) mlp1
    for (int t = 0; t < LSEQ; ++t) {
      u16* chi = (t & 1) ? c1h : c0h;
      u16* clo = (t & 1) ? c1l : c0l;
      u16* nhi = (t & 1) ? c0h : c1h;
      u16* nlo = (t & 1) ? c0l : c1l;
      for (int s = 0; s < 3; ++s) {
        {  // mlp1 (seg0-B preloaded)
          const int n0 = l << 5;
          gemm_phase<1, 16, true>(Sah, Sal, Sbh, Sbl,
                                  chi, clo, HID, m0, w1h, w1l, 512, n0,
                                  b1, h1h, h1l, data, t, tid, preh, prel);
        }
        asm volatile("" ::: "memory");   // keep prefetch issue after EPI stores
        if (l < 16) pre_w(w2h, w2l, 1024, l << 5);
        else { if (s < 2) pre_w(w1h, w1l, 512, l << 5); else pre_g(); }
        slice_barrier_p12(line, ++rnd);
        if (l < 16) {
          {  // mlp2 (seg0-B preloaded)
            const int n0 = l << 5;
            gemm_phase<2, 32, true>(Sah, Sal, Sbh, Sbl,
                                    h1h, h1l, HID, m0, w2h, w2l, 1024, n0,
                                    b2, chi, clo, data, t, tid, preh, prel);
          }
          asm volatile("" ::: "memory");
          if (s < 2) pre_w(w1h, w1l, 512, l << 5); else pre_g();
          slice_barrier_p12(line, ++rnd);
        } else {
          // no stores since last drain; prior prefetch (<=12) stays in flight
          slice_barrier_p12(line, ++rnd);
        }
      }
      gru_phase<true>(pool, chi, clo, whh, whhh, whhl, wih, wihh, wihl,
                      bih, bhh, data, t, nhi, nlo, out, l << 5, m0, tid, preh, prel);
      if (t + 1 < LSEQ) {
        asm volatile("" ::: "memory");
        pre_w(w1h, w1l, 512, l << 5);
        slice_barrier_p12(line, ++rnd);
      }
    }
  } else {
    for (int t = 0; t < LSEQ; ++t) {
      u16* chi = (t & 1) ? c1h : c0h;
      u16* clo = (t & 1) ? c1l : c0l;
      u16* nhi = (t & 1) ? c0h : c1h;
      u16* nlo = (t & 1) ? c0l : c1l;
      for (int s = 0; s < 3; ++s) {
        {
          const int n0 = l << 5;
          gemm_phase<1, 16, false>(Sah, Sal, Sbh, Sbl,
                                   chi, clo, HID, m0, w1h, w1l, 512, n0,
                                   b1, h1h, h1l, data, t, tid, nullptr, nullptr);
        }
        slice_barrier(line, ++rnd);
        if (l < 16) {
          const int n0 = l << 5;
          gemm_phase<2, 32, false>(Sah, Sal, Sbh, Sbl,
                                   h1h, h1l, HID, m0, w2h, w2l, 1024, n0,
                                   b2, chi, clo, data, t, tid, nullptr, nullptr);
        }
        slice_barrier(line, ++rnd);
      }
      gru_phase<false>(pool, chi, clo, whh, whhh, whhl, wih, wihh, wihl,
                       bih, bhh, data, t, nhi, nlo, out, l << 5, m0, tid, nullptr, nullptr);
      if (t + 1 < LSEQ) slice_barrier(line, ++rnd);
    }
  }
}

extern "C" void kernel_launch(void* const* d_in, const int* in_sizes, int n_in,
                              void* d_out, int out_size, void* d_ws, size_t ws_size,
                              hipStream_t stream)
{
  const float* data = (const float*)d_in[0];
  const float* w1   = (const float*)d_in[1];
  const float* b1   = (const float*)d_in[2];
  const float* w2   = (const float*)d_in[3];
  const float* b2   = (const float*)d_in[4];
  const float* wih  = (const float*)d_in[5];
  const float* bih  = (const float*)d_in[6];
  const float* whh  = (const float*)d_in[7];
  const float* bhh  = (const float*)d_in[8];
  float* out = (float*)d_out;

  char* w = (char*)d_ws;
  auto alloc = [&](size_t bytes) { char* p = w; w += bytes; return p; };
  u16* w1h = (u16*)alloc((size_t)512 * 1024 * 2);   // [1024 n][512 k] planes
  u16* w1l = (u16*)alloc((size_t)512 * 1024 * 2);
  u16* w2h = (u16*)alloc((size_t)512 * 1024 * 2);   // [512 n][1024 k] planes
  u16* w2l = (u16*)alloc((size_t)512 * 1024 * 2);
  u16* c0h = (u16*)alloc((size_t)BATCH * HID * 2);
  u16* c0l = (u16*)alloc((size_t)BATCH * HID * 2);
  u16* c1h = (u16*)alloc((size_t)BATCH * HID * 2);
  u16* c1l = (u16*)alloc((size_t)BATCH * HID * 2);
  u16* h1h = (u16*)alloc((size_t)BATCH * HID * 2);
  u16* h1l = (u16*)alloc((size_t)BATCH * HID * 2);
  unsigned* bar = (unsigned*)alloc(4096);            // 16 counter lines, 256B apart
  size_t base = (size_t)(w - (char*)d_ws);
  size_t need_opt = base + 2 * ((size_t)3072 * 1024 * 2) + 2 * ((size_t)3072 * 256 * 2);
  bool planes = ws_size >= need_opt;
  u16 *whhh = nullptr, *whhl = nullptr, *wihh = nullptr, *wihl = nullptr;
  if (planes) {
    whhh = (u16*)alloc((size_t)3072 * 1024 * 2);
    whhl = (u16*)alloc((size_t)3072 * 1024 * 2);
    wihh = (u16*)alloc((size_t)3072 * 256 * 2);
    wihl = (u16*)alloc((size_t)3072 * 256 * 2);
  }

  tsplit_k<<<dim3(512 / 32, 1024 / 32), 256, 0, stream>>>(w1, w1h, w1l, 512, 1024);
  tsplit_k<<<dim3(1024 / 32, 512 / 32), 256, 0, stream>>>(w2, w2h, w2l, 1024, 512);
  if (planes) {
    esplit_k<<<dim3((3072 * 1024) / 1024), 256, 0, stream>>>(whh, whhh, whhl);
    esplit_k<<<dim3((3072 * 256) / 1024), 256, 0, stream>>>(wih, wihh, wihl);
  }
  init_k<<<dim3(256), 256, 0, stream>>>(c0h, c0l, bar);

  if (planes) {
    fused_seq_k<true><<<dim3(NBLK), dim3(256), 0, stream>>>(
        w1h, w1l, w2h, w2l, b1, b2, c0h, c0l, c1h, c1l, h1h, h1l,
        whh, whhh, whhl, wih, wihh, wihl, bih, bhh, data, out, bar);
  } else {
    fused_seq_k<false><<<dim3(NBLK), dim3(256), 0, stream>>>(
        w1h, w1l, w2h, w2l, b1, b2, c0h, c0l, c1h, c1l, h1h, h1l,
        whh, whhh, whhl, wih, wihh, wihl, bih, bhh, data, out, bar);
  }
}

// Round 11
// 3995.056 us; speedup vs baseline: 1.0382x; 1.0382x over previous
//
#include <hip/hip_runtime.h>

#define LSEQ 50
#define BATCH 256
#define DIN 256
#define LAT 512
#define HID 1024
#define ROWSTRIDE 257  // D_IN + 1 (dt channel)
#define NBLK 256

typedef __attribute__((ext_vector_type(8))) short s16x8;
typedef __attribute__((ext_vector_type(4))) float f32x4;
using u16 = unsigned short;
using u64 = unsigned long long;

__device__ __forceinline__ u16 bfhi(float v) {
  union { float f; unsigned u; } a; a.f = v;
  return (u16)((a.u + 0x7FFFu + ((a.u >> 16) & 1u)) >> 16);
}
__device__ __forceinline__ void split2(float v, u16& h, u16& l) {
  u16 hu = bfhi(v);
  union { unsigned u; float f; } hf; hf.u = ((unsigned)hu) << 16;
  h = hu; l = bfhi(v - hf.f);
}
__device__ __forceinline__ float p2f(u16 h, u16 l) {
  union { unsigned u; float f; } a, b;
  a.u = ((unsigned)h) << 16; b.u = ((unsigned)l) << 16;
  return a.f + b.f;
}
__device__ __forceinline__ float sigmoidf_(float x) { return 1.f / (1.f + __expf(-x)); }
__device__ __forceinline__ f32x4 mfma16(s16x8 a, s16x8 b, f32x4 c) {
  return __builtin_amdgcn_mfma_f32_16x16x32_bf16(a, b, c, 0, 0, 0);
}
__device__ __forceinline__ f32x4 mfma3(s16x8 ah, s16x8 al, s16x8 bh, s16x8 bl, f32x4 c) {
  c = mfma16(ah, bh, c); c = mfma16(ah, bl, c); c = mfma16(al, bh, c); return c;
}
__device__ __forceinline__ ushort4 ldu4(const u16* p) { return *(const ushort4*)p; }
__device__ __forceinline__ void stu4(u16* p, ushort4 v) { *(ushort4*)p = v; }

// ---------- coherent (LLC-authoritative) accessors for cross-block state ----------
__device__ __forceinline__ ushort4 ldu4c(const u16* p) {
  u64 v = __hip_atomic_load((const u64*)p, __ATOMIC_RELAXED, __HIP_MEMORY_SCOPE_AGENT);
  union { u64 q; ushort4 s; } u; u.q = v; return u.s;
}
__device__ __forceinline__ u16 ldu16c(const u16* p) {
  return __hip_atomic_load(p, __ATOMIC_RELAXED, __HIP_MEMORY_SCOPE_AGENT);
}
__device__ __forceinline__ void stu16c(u16* p, u16 v) {
  __hip_atomic_store(p, v, __ATOMIC_RELAXED, __HIP_MEMORY_SCOPE_AGENT);
}

// ---------- in-phase barrier: LDS-ordered only ----------
__device__ __forceinline__ void kbar() {
  asm volatile("s_waitcnt lgkmcnt(0)" ::: "memory");
  __builtin_amdgcn_s_barrier();
}

// ---------- slice barrier (round-6 verbatim) ----------
__device__ __forceinline__ void slice_barrier(unsigned* line, unsigned k) {
  asm volatile("s_waitcnt vmcnt(0)" ::: "memory");
  __syncthreads();
  if (threadIdx.x == 0) {
    __hip_atomic_fetch_add(line, 1u, __ATOMIC_RELAXED, __HIP_MEMORY_SCOPE_AGENT);
    const unsigned tgt = k * 32u;
    while (__hip_atomic_load(line, __ATOMIC_RELAXED, __HIP_MEMORY_SCOPE_AGENT) < tgt) {
      __builtin_amdgcn_s_sleep(1);
    }
  }
  __syncthreads();
}

// ---------- preprocessing (unchanged) ----------
__global__ __launch_bounds__(256) void tsplit_k(const float* __restrict__ W,
    u16* __restrict__ Thi, u16* __restrict__ Tlo, int K, int N)
{
  __shared__ unsigned Ts[32][33];
  const int bk = blockIdx.x * 32, bn = blockIdx.y * 32;
  const int t = threadIdx.x;
  const int n_l = t & 31, k_l4 = (t >> 5) * 4;
  #pragma unroll
  for (int i = 0; i < 4; i++) {
    float v = W[(size_t)(bk + k_l4 + i) * N + bn + n_l];
    u16 h, l; split2(v, h, l);
    Ts[k_l4 + i][n_l] = ((unsigned)h << 16) | l;
  }
  __syncthreads();
  const int k_l = t & 31, n_l2 = t >> 5;
  #pragma unroll
  for (int i = 0; i < 4; i++) {
    int nn = n_l2 + 8 * i;
    unsigned u = Ts[k_l][nn];
    size_t o = (size_t)(bn + nn) * K + bk + k_l;
    Thi[o] = (u16)(u >> 16);
    Tlo[o] = (u16)(u & 0xFFFFu);
  }
}

__global__ __launch_bounds__(256) void esplit_k(const float* __restrict__ W,
    u16* __restrict__ Phi, u16* __restrict__ Plo)
{
  size_t i4 = ((size_t)blockIdx.x * 256 + threadIdx.x) * 4;
  float4 v = *(const float4*)&W[i4];
  u16 h[4], l[4];
  split2(v.x, h[0], l[0]); split2(v.y, h[1], l[1]);
  split2(v.z, h[2], l[2]); split2(v.w, h[3], l[3]);
  *(ushort4*)&Phi[i4] = make_ushort4(h[0], h[1], h[2], h[3]);
  *(ushort4*)&Plo[i4] = make_ushort4(l[0], l[1], l[2], l[3]);
}

__global__ __launch_bounds__(256) void init_k(u16* __restrict__ c0h, u16* __restrict__ c0l,
                                              unsigned* __restrict__ bar)
{
  size_t i4 = ((size_t)blockIdx.x * 256 + threadIdx.x) * 4;
  *(ushort4*)&c0h[i4] = make_ushort4(0, 0, 0, 0);
  *(ushort4*)&c0l[i4] = make_ushort4(0, 0, 0, 0);
  if (blockIdx.x == 0 && threadIdx.x < 16) bar[threadIdx.x * 64] = 0u;
}

// ---------- gemm phase: 2-deep register prefetch, K-segment ROTATION per block ----------
// Rotation decorrelates the slice's 32 blocks so they don't hit the same LLC lines
// in lockstep (state reads are sc-atomics -> LLC-served; same-address lockstep
// collapses to single-slice LLC BW). Accumulation order change is benign (f32
// reassociation, 7x absmax headroom).
template<int EPI, int NITER>
__device__ __forceinline__ void gemm_phase(
    u16* __restrict__ Sah, u16* __restrict__ Sal,
    u16* __restrict__ Sbh, u16* __restrict__ Sbl,
    const u16* __restrict__ Ahi, const u16* __restrict__ Alo, int ldA, int m0,
    const u16* __restrict__ Bhi, const u16* __restrict__ Blo, int ldB, int n0,
    const float* __restrict__ bias,
    u16* __restrict__ Ohi, u16* __restrict__ Olo,
    const float* __restrict__ data, int t, int tid, int rot)
{
  constexpr int NSEG = NITER / 4;   // 4 (mlp1) or 8 (mlp2), power of two
  const int lane = tid & 63, wave = tid >> 6;
  const int wm = (wave >> 1) << 4, wn = (wave & 1) << 4;
  const int lr = lane & 15, lq = lane >> 4;
  const int srow = tid >> 3, sk4 = (tid & 7) << 2;
  const int sidx = srow * 40 + sk4;
  const size_t rowA = (size_t)(m0 + srow) * ldA + sk4;
  const size_t rowB = (size_t)(n0 + srow) * ldB + sk4;
  const int fa = (wm + lr) * 40 + lq * 8;
  const int fb = (wn + lr) * 40 + lq * 8;
  f32x4 acc0 = {0,0,0,0}, acc1 = {0,0,0,0};

  ushort4 ah0[4], al0[4], bh0[4], bl0[4];
  ushort4 ah1[4], al1[4], bh1[4], bl1[4];

  auto rs = [&](int p) { return (p + rot) & (NSEG - 1); };

  auto load0 = [&](int seg) {
    #pragma unroll
    for (int d = 0; d < 4; ++d) {
      const int k0 = (seg * 4 + d) << 5;
      ah0[d] = ldu4c(&Ahi[rowA + k0]); al0[d] = ldu4c(&Alo[rowA + k0]);
      bh0[d] = ldu4(&Bhi[rowB + k0]);  bl0[d] = ldu4(&Blo[rowB + k0]);
    }
  };
  auto load1 = [&](int seg) {
    #pragma unroll
    for (int d = 0; d < 4; ++d) {
      const int k0 = (seg * 4 + d) << 5;
      ah1[d] = ldu4c(&Ahi[rowA + k0]); al1[d] = ldu4c(&Alo[rowA + k0]);
      bh1[d] = ldu4(&Bhi[rowB + k0]);  bl1[d] = ldu4(&Blo[rowB + k0]);
    }
  };
  auto write0 = [&]() {
    #pragma unroll
    for (int d = 0; d < 4; ++d) {
      stu4(&Sah[d * 1280 + sidx], ah0[d]); stu4(&Sal[d * 1280 + sidx], al0[d]);
      stu4(&Sbh[d * 1280 + sidx], bh0[d]); stu4(&Sbl[d * 1280 + sidx], bl0[d]);
    }
  };
  auto write1 = [&]() {
    #pragma unroll
    for (int d = 0; d < 4; ++d) {
      stu4(&Sah[5120 + d * 1280 + sidx], ah1[d]); stu4(&Sal[5120 + d * 1280 + sidx], al1[d]);
      stu4(&Sbh[5120 + d * 1280 + sidx], bh1[d]); stu4(&Sbl[5120 + d * 1280 + sidx], bl1[d]);
    }
  };
  auto compute = [&](int g) {
    #pragma unroll
    for (int d = 0; d < 4; ++d) {
      const int o = g * 5120 + d * 1280;
      s16x8 ah = *(const s16x8*)&Sah[o + fa];
      s16x8 al = *(const s16x8*)&Sal[o + fa];
      s16x8 bh = *(const s16x8*)&Sbh[o + fb];
      s16x8 bl = *(const s16x8*)&Sbl[o + fb];
      if (d & 1) acc1 = mfma3(ah, al, bh, bl, acc1);
      else       acc0 = mfma3(ah, al, bh, bl, acc0);
    }
  };

  load0(rs(0));
  load1(rs(1));
  write0();
  kbar();
  for (int p = 0; p < NSEG; p += 2) {
    if (p + 2 < NSEG) load0(rs(p + 2));
    compute(0);
    write1();
    kbar();
    if (p + 3 < NSEG) load1(rs(p + 3));
    compute(1);
    if (p + 2 < NSEG) write0();
    kbar();
  }

  #pragma unroll
  for (int r = 0; r < 4; ++r) {
    const int row = m0 + wm + lq * 4 + r;
    const int col = n0 + wn + lr;
    float v = acc0[r] + acc1[r] + bias[col];
    size_t o = (size_t)row * HID + col;
    if (EPI == 1) {
      float h1 = tanhf(v);
      u16 h, l; split2(h1, h, l);
      stu16c(&Ohi[o], h); stu16c(&Olo[o], l);
    } else {
      float dt3 = data[(size_t)(t * BATCH + row) * ROWSTRIDE + DIN] * (1.f / 3.f);
      float y = p2f(ldu16c(&Ohi[o]), ldu16c(&Olo[o])) + v * dt3;
      u16 h, l; split2(y, h, l);
      stu16c(&Ohi[o], h); stu16c(&Olo[o], l);
    }
  }
}

// ---------- fused GRU phase: 2-deep pipeline, rotated segments ----------
template<bool PLANES>
__device__ __forceinline__ void gru_phase(
    u16* pool,
    const u16* __restrict__ chi, const u16* __restrict__ clo,
    const float* __restrict__ whh, const u16* __restrict__ whhh, const u16* __restrict__ whhl,
    const float* __restrict__ wih, const u16* __restrict__ wihh, const u16* __restrict__ wihl,
    const float* __restrict__ bih, const float* __restrict__ bhh,
    const float* __restrict__ data, int t,
    u16* __restrict__ nhi, u16* __restrict__ nlo,
    float* __restrict__ out, int gc0, int m0, int tid, int lblk)
{
  u16* sAh = pool;
  u16* sAl = pool + 5120;
  u16* sBh = pool + 10240;
  u16* sBl = pool + 25600;
  const int lane = tid & 63, wave = tid >> 6;
  const int wm = (wave >> 1) << 4, wn = (wave & 1) << 4;
  const int lr = lane & 15, lq = lane >> 4;
  const int srow = tid >> 3, sk4 = (tid & 7) << 2;
  const int sidx = srow * 40 + sk4;
  const int fa = (wm + lr) * 40 + lq * 8;
  const int fbn = (wn + lr) * 40 + lq * 8;
  f32x4 aR0 = {0,0,0,0}, aR1 = {0,0,0,0};
  f32x4 aZ0 = {0,0,0,0}, aZ1 = {0,0,0,0};
  f32x4 aNh0 = {0,0,0,0}, aNh1 = {0,0,0,0};
  f32x4 aNi0 = {0,0,0,0}, aNi1 = {0,0,0,0};

  // ===== gh: K=1024 over (chi | whh), 32 tiles = 16 segments of 2, rot = l&15 =====
  {
    const int rot = lblk & 15;
    const size_t rowA = (size_t)(m0 + srow) * HID + sk4;
    const size_t rB0 = (size_t)(0 * 1024 + gc0 + srow) * 1024 + sk4;
    const size_t rB1 = (size_t)(1 * 1024 + gc0 + srow) * 1024 + sk4;
    const size_t rB2 = (size_t)(2 * 1024 + gc0 + srow) * 1024 + sk4;
    ushort4 Ah0[2], Al0[2], Bh0[2][3], Bl0[2][3];
    ushort4 Ah1[2], Al1[2], Bh1[2][3], Bl1[2][3];
    float4  F0[2][3], F1[2][3];

    auto rs = [&](int p) { return (p + rot) & 15; };

    auto load0 = [&](int seg) {
      #pragma unroll
      for (int j = 0; j < 2; ++j) {
        const int k0 = (seg * 2 + j) << 5;
        Ah0[j] = ldu4c(&chi[rowA + k0]); Al0[j] = ldu4c(&clo[rowA + k0]);
        if (PLANES) {
          Bh0[j][0] = ldu4(&whhh[rB0 + k0]); Bl0[j][0] = ldu4(&whhl[rB0 + k0]);
          Bh0[j][1] = ldu4(&whhh[rB1 + k0]); Bl0[j][1] = ldu4(&whhl[rB1 + k0]);
          Bh0[j][2] = ldu4(&whhh[rB2 + k0]); Bl0[j][2] = ldu4(&whhl[rB2 + k0]);
        } else {
          F0[j][0] = *(const float4*)&whh[rB0 + k0];
          F0[j][1] = *(const float4*)&whh[rB1 + k0];
          F0[j][2] = *(const float4*)&whh[rB2 + k0];
        }
      }
    };
    auto load1 = [&](int seg) {
      #pragma unroll
      for (int j = 0; j < 2; ++j) {
        const int k0 = (seg * 2 + j) << 5;
        Ah1[j] = ldu4c(&chi[rowA + k0]); Al1[j] = ldu4c(&clo[rowA + k0]);
        if (PLANES) {
          Bh1[j][0] = ldu4(&whhh[rB0 + k0]); Bl1[j][0] = ldu4(&whhl[rB0 + k0]);
          Bh1[j][1] = ldu4(&whhh[rB1 + k0]); Bl1[j][1] = ldu4(&whhl[rB1 + k0]);
          Bh1[j][2] = ldu4(&whhh[rB2 + k0]); Bl1[j][2] = ldu4(&whhl[rB2 + k0]);
        } else {
          F1[j][0] = *(const float4*)&whh[rB0 + k0];
          F1[j][1] = *(const float4*)&whh[rB1 + k0];
          F1[j][2] = *(const float4*)&whh[rB2 + k0];
        }
      }
    };
    auto write0 = [&]() {
      #pragma unroll
      for (int j = 0; j < 2; ++j) {
        stu4(&sAh[j * 1280 + sidx], Ah0[j]); stu4(&sAl[j * 1280 + sidx], Al0[j]);
        #pragma unroll
        for (int g = 0; g < 3; ++g) {
          if (PLANES) {
            stu4(&sBh[j * 3840 + g * 1280 + sidx], Bh0[j][g]);
            stu4(&sBl[j * 3840 + g * 1280 + sidx], Bl0[j][g]);
          } else {
            float4 w4 = F0[j][g];
            u16 h0,l0,h1,l1,h2,l2,h3,l3;
            split2(w4.x,h0,l0); split2(w4.y,h1,l1); split2(w4.z,h2,l2); split2(w4.w,h3,l3);
            stu4(&sBh[j * 3840 + g * 1280 + sidx], make_ushort4(h0,h1,h2,h3));
            stu4(&sBl[j * 3840 + g * 1280 + sidx], make_ushort4(l0,l1,l2,l3));
          }
        }
      }
    };
    auto write1 = [&]() {
      #pragma unroll
      for (int j = 0; j < 2; ++j) {
        stu4(&sAh[(2 + j) * 1280 + sidx], Ah1[j]); stu4(&sAl[(2 + j) * 1280 + sidx], Al1[j]);
        #pragma unroll
        for (int g = 0; g < 3; ++g) {
          if (PLANES) {
            stu4(&sBh[(2 + j) * 3840 + g * 1280 + sidx], Bh1[j][g]);
            stu4(&sBl[(2 + j) * 3840 + g * 1280 + sidx], Bl1[j][g]);
          } else {
            float4 w4 = F1[j][g];
            u16 h0,l0,h1,l1,h2,l2,h3,l3;
            split2(w4.x,h0,l0); split2(w4.y,h1,l1); split2(w4.z,h2,l2); split2(w4.w,h3,l3);
            stu4(&sBh[(2 + j) * 3840 + g * 1280 + sidx], make_ushort4(h0,h1,h2,h3));
            stu4(&sBl[(2 + j) * 3840 + g * 1280 + sidx], make_ushort4(l0,l1,l2,l3));
          }
        }
      }
    };
    auto compute = [&](int grp) {
      #pragma unroll
      for (int j = 0; j < 2; ++j) {
        const int slot = grp * 2 + j;
        const int sa = slot * 1280 + fa;
        const int sb = slot * 3840 + fbn;
        s16x8 ah = *(const s16x8*)&sAh[sa];
        s16x8 al = *(const s16x8*)&sAl[sa];
        #pragma unroll
        for (int g = 0; g < 3; ++g) {
          s16x8 bh = *(const s16x8*)&sBh[sb + g * 1280];
          s16x8 bl = *(const s16x8*)&sBl[sb + g * 1280];
          if (j) {
            if (g == 0) aR1 = mfma3(ah, al, bh, bl, aR1);
            else if (g == 1) aZ1 = mfma3(ah, al, bh, bl, aZ1);
            else aNh1 = mfma3(ah, al, bh, bl, aNh1);
          } else {
            if (g == 0) aR0 = mfma3(ah, al, bh, bl, aR0);
            else if (g == 1) aZ0 = mfma3(ah, al, bh, bl, aZ0);
            else aNh0 = mfma3(ah, al, bh, bl, aNh0);
          }
        }
      }
    };

    load0(rs(0)); load1(rs(1)); write0(); kbar();
    for (int p = 0; p < 16; p += 2) {
      if (p + 2 < 16) load0(rs(p + 2));
      compute(0);
      write1();
      kbar();
      if (p + 3 < 16) load1(rs(p + 3));
      compute(1);
      if (p + 2 < 16) write0();
      kbar();
    }
  }

  // ===== gi: K=256 over (x_t | wih), 8 tiles = 4 segments of 2, rot = l&3 =====
  {
    const int rot = lblk & 3;
    const size_t rowX = (size_t)(t * BATCH + m0 + srow) * ROWSTRIDE + sk4;
    const size_t rB0 = (size_t)(0 * 1024 + gc0 + srow) * 256 + sk4;
    const size_t rB1 = (size_t)(1 * 1024 + gc0 + srow) * 256 + sk4;
    const size_t rB2 = (size_t)(2 * 1024 + gc0 + srow) * 256 + sk4;
    float4  X0[2], X1[2];
    ushort4 Bh0[2][3], Bl0[2][3], Bh1[2][3], Bl1[2][3];
    float4  F0[2][3], F1[2][3];

    auto rs = [&](int p) { return (p + rot) & 3; };

    auto load0 = [&](int seg) {
      #pragma unroll
      for (int j = 0; j < 2; ++j) {
        const int k0 = (seg * 2 + j) << 5;
        X0[j] = *(const float4*)&data[rowX + k0];
        if (PLANES) {
          Bh0[j][0] = ldu4(&wihh[rB0 + k0]); Bl0[j][0] = ldu4(&wihl[rB0 + k0]);
          Bh0[j][1] = ldu4(&wihh[rB1 + k0]); Bl0[j][1] = ldu4(&wihl[rB1 + k0]);
          Bh0[j][2] = ldu4(&wihh[rB2 + k0]); Bl0[j][2] = ldu4(&wihl[rB2 + k0]);
        } else {
          F0[j][0] = *(const float4*)&wih[rB0 + k0];
          F0[j][1] = *(const float4*)&wih[rB1 + k0];
          F0[j][2] = *(const float4*)&wih[rB2 + k0];
        }
      }
    };
    auto load1 = [&](int seg) {
      #pragma unroll
      for (int j = 0; j < 2; ++j) {
        const int k0 = (seg * 2 + j) << 5;
        X1[j] = *(const float4*)&data[rowX + k0];
        if (PLANES) {
          Bh1[j][0] = ldu4(&wihh[rB0 + k0]); Bl1[j][0] = ldu4(&wihl[rB0 + k0]);
          Bh1[j][1] = ldu4(&wihh[rB1 + k0]); Bl1[j][1] = ldu4(&wihl[rB1 + k0]);
          Bh1[j][2] = ldu4(&wihh[rB2 + k0]); Bl1[j][2] = ldu4(&wihl[rB2 + k0]);
        } else {
          F1[j][0] = *(const float4*)&wih[rB0 + k0];
          F1[j][1] = *(const float4*)&wih[rB1 + k0];
          F1[j][2] = *(const float4*)&wih[rB2 + k0];
        }
      }
    };
    auto writeX = [&](const float4* X, int base) {
      #pragma unroll
      for (int j = 0; j < 2; ++j) {
        u16 xh[4], xl[4];
        split2(X[j].x, xh[0], xl[0]); split2(X[j].y, xh[1], xl[1]);
        split2(X[j].z, xh[2], xl[2]); split2(X[j].w, xh[3], xl[3]);
        stu4(&sAh[(base + j) * 1280 + sidx], make_ushort4(xh[0], xh[1], xh[2], xh[3]));
        stu4(&sAl[(base + j) * 1280 + sidx], make_ushort4(xl[0], xl[1], xl[2], xl[3]));
      }
    };
    auto write0 = [&]() {
      writeX(X0, 0);
      #pragma unroll
      for (int j = 0; j < 2; ++j)
        #pragma unroll
        for (int g = 0; g < 3; ++g) {
          if (PLANES) {
            stu4(&sBh[j * 3840 + g * 1280 + sidx], Bh0[j][g]);
            stu4(&sBl[j * 3840 + g * 1280 + sidx], Bl0[j][g]);
          } else {
            float4 w4 = F0[j][g];
            u16 h0,l0,h1,l1,h2,l2,h3,l3;
            split2(w4.x,h0,l0); split2(w4.y,h1,l1); split2(w4.z,h2,l2); split2(w4.w,h3,l3);
            stu4(&sBh[j * 3840 + g * 1280 + sidx], make_ushort4(h0,h1,h2,h3));
            stu4(&sBl[j * 3840 + g * 1280 + sidx], make_ushort4(l0,l1,l2,l3));
          }
        }
    };
    auto write1 = [&]() {
      writeX(X1, 2);
      #pragma unroll
      for (int j = 0; j < 2; ++j)
        #pragma unroll
        for (int g = 0; g < 3; ++g) {
          if (PLANES) {
            stu4(&sBh[(2 + j) * 3840 + g * 1280 + sidx], Bh1[j][g]);
            stu4(&sBl[(2 + j) * 3840 + g * 1280 + sidx], Bl1[j][g]);
          } else {
            float4 w4 = F1[j][g];
            u16 h0,l0,h1,l1,h2,l2,h3,l3;
            split2(w4.x,h0,l0); split2(w4.y,h1,l1); split2(w4.z,h2,l2); split2(w4.w,h3,l3);
            stu4(&sBh[(2 + j) * 3840 + g * 1280 + sidx], make_ushort4(h0,h1,h2,h3));
            stu4(&sBl[(2 + j) * 3840 + g * 1280 + sidx], make_ushort4(l0,l1,l2,l3));
          }
        }
    };
    auto compute = [&](int grp) {
      #pragma unroll
      for (int j = 0; j < 2; ++j) {
        const int slot = grp * 2 + j;
        const int sa = slot * 1280 + fa;
        const int sb = slot * 3840 + fbn;
        s16x8 ah = *(const s16x8*)&sAh[sa];
        s16x8 al = *(const s16x8*)&sAl[sa];
        #pragma unroll
        for (int g = 0; g < 3; ++g) {
          s16x8 bh = *(const s16x8*)&sBh[sb + g * 1280];
          s16x8 bl = *(const s16x8*)&sBl[sb + g * 1280];
          if (j) {
            if (g == 0) aR1 = mfma3(ah, al, bh, bl, aR1);
            else if (g == 1) aZ1 = mfma3(ah, al, bh, bl, aZ1);
            else aNi1 = mfma3(ah, al, bh, bl, aNi1);
          } else {
            if (g == 0) aR0 = mfma3(ah, al, bh, bl, aR0);
            else if (g == 1) aZ0 = mfma3(ah, al, bh, bl, aZ0);
            else aNi0 = mfma3(ah, al, bh, bl, aNi0);
          }
        }
      }
    };

    load0(rs(0)); load1(rs(1)); write0(); kbar();
    for (int p = 0; p < 4; p += 2) {
      if (p + 2 < 4) load0(rs(p + 2));
      compute(0);
      write1();
      kbar();
      if (p + 3 < 4) load1(rs(p + 3));
      compute(1);
      if (p + 2 < 4) write0();
      kbar();
    }
  }

  const f32x4 aR = aR0 + aR1, aZ = aZ0 + aZ1, aNh = aNh0 + aNh1, aNi = aNi0 + aNi1;

  // ===== epilogue =====
  #pragma unroll
  for (int r = 0; r < 4; ++r) {
    const int row = m0 + wm + lq * 4 + r;
    const int jg = gc0 + wn + lr;
    float rr = sigmoidf_(aR[r] + bih[jg] + bhh[jg]);
    float zz = sigmoidf_(aZ[r] + bih[1024 + jg] + bhh[1024 + jg]);
    float nn = tanhf(aNi[r] + bih[2048 + jg] + rr * (aNh[r] + bhh[2048 + jg]));
    size_t oh = (size_t)row * HID + jg;
    float hv = p2f(ldu16c(&chi[oh]), ldu16c(&clo[oh]));
    float val = (1.f - zz) * nn + zz * hv;
    out[(size_t)LSEQ * BATCH * LAT + oh] = val;        // output 1 (new_h)
    if (jg < LAT) {
      out[((size_t)t * BATCH + row) * LAT + jg] = val; // output 0
      u16 h, l; split2(val, h, l);
      stu16c(&nhi[oh], h); stu16c(&nhi[oh + LAT], h);
      stu16c(&nlo[oh], l); stu16c(&nlo[oh + LAT], l);
    }
  }
}

// ---------- one persistent kernel, 8 independent batch-row slices ----------
template<bool PLANES>
__global__ __launch_bounds__(256) void fused_seq_k(
    const u16* __restrict__ w1h, const u16* __restrict__ w1l,
    const u16* __restrict__ w2h, const u16* __restrict__ w2l,
    const float* __restrict__ b1, const float* __restrict__ b2,
    u16* __restrict__ c0h, u16* __restrict__ c0l,
    u16* __restrict__ c1h, u16* __restrict__ c1l,
    u16* __restrict__ h1h, u16* __restrict__ h1l,
    const float* __restrict__ whh, const u16* __restrict__ whhh, const u16* __restrict__ whhl,
    const float* __restrict__ wih, const u16* __restrict__ wihh, const u16* __restrict__ wihl,
    const float* __restrict__ bih, const float* __restrict__ bhh,
    const float* __restrict__ data, float* __restrict__ out,
    unsigned* __restrict__ bar)
{
  __shared__ u16 pool[40960];   // 80 KB
  const int b = blockIdx.x;
  const int tid = threadIdx.x;
  const int slice = b >> 5;
  const int l = b & 31;
  const int m0 = slice << 5;
  unsigned* line = bar + slice * 64;
  unsigned rnd = 0;

  u16* Sah = pool;
  u16* Sal = pool + 10240;
  u16* Sbh = pool + 20480;
  u16* Sbl = pool + 30720;

  for (int t = 0; t < LSEQ; ++t) {
    u16* chi = (t & 1) ? c1h : c0h;
    u16* clo = (t & 1) ? c1l : c0l;
    u16* nhi = (t & 1) ? c0h : c1h;
    u16* nlo = (t & 1) ? c0l : c1l;
    for (int s = 0; s < 3; ++s) {
      {  // mlp1: h1 = tanh(y @ w1 + b1), K=512, rot over 4 segments
        const int n0 = l << 5;
        gemm_phase<1, 16>(Sah, Sal, Sbh, Sbl,
                          chi, clo, HID, m0, w1h, w1l, 512, n0,
                          b1, h1h, h1l, data, t, tid, l & 3);
      }
      slice_barrier(line, ++rnd);
      if (l < 16) {  // mlp2: y += (h1 @ w2 + b2)*dt/3, K=1024, rot over 8 segments
        const int n0 = l << 5;
        gemm_phase<2, 32>(Sah, Sal, Sbh, Sbl,
                          h1h, h1l, HID, m0, w2h, w2l, 1024, n0,
                          b2, chi, clo, data, t, tid, l & 7);
      }
      slice_barrier(line, ++rnd);
    }
    gru_phase<PLANES>(pool, chi, clo, whh, whhh, whhl, wih, wihh, wihl,
                      bih, bhh, data, t, nhi, nlo, out, l << 5, m0, tid, l);
    if (t + 1 < LSEQ) slice_barrier(line, ++rnd);
  }
}

extern "C" void kernel_launch(void* const* d_in, const int* in_sizes, int n_in,
                              void* d_out, int out_size, void* d_ws, size_t ws_size,
                              hipStream_t stream)
{
  const float* data = (const float*)d_in[0];
  const float* w1   = (const float*)d_in[1];
  const float* b1   = (const float*)d_in[2];
  const float* w2   = (const float*)d_in[3];
  const float* b2   = (const float*)d_in[4];
  const float* wih  = (const float*)d_in[5];
  const float* bih  = (const float*)d_in[6];
  const float* whh  = (const float*)d_in[7];
  const float* bhh  = (const float*)d_in[8];
  float* out = (float*)d_out;

  char* w = (char*)d_ws;
  auto alloc = [&](size_t bytes) { char* p = w; w += bytes; return p; };
  u16* w1h = (u16*)alloc((size_t)512 * 1024 * 2);   // [1024 n][512 k] planes
  u16* w1l = (u16*)alloc((size_t)512 * 1024 * 2);
  u16* w2h = (u16*)alloc((size_t)512 * 1024 * 2);   // [512 n][1024 k] planes
  u16* w2l = (u16*)alloc((size_t)512 * 1024 * 2);
  u16* c0h = (u16*)alloc((size_t)BATCH * HID * 2);
  u16* c0l = (u16*)alloc((size_t)BATCH * HID * 2);
  u16* c1h = (u16*)alloc((size_t)BATCH * HID * 2);
  u16* c1l = (u16*)alloc((size_t)BATCH * HID * 2);
  u16* h1h = (u16*)alloc((size_t)BATCH * HID * 2);
  u16* h1l = (u16*)alloc((size_t)BATCH * HID * 2);
  unsigned* bar = (unsigned*)alloc(4096);            // 16 counter lines, 256B apart
  size_t base = (size_t)(w - (char*)d_ws);
  size_t need_opt = base + 2 * ((size_t)3072 * 1024 * 2) + 2 * ((size_t)3072 * 256 * 2);
  bool planes = ws_size >= need_opt;
  u16 *whhh = nullptr, *whhl = nullptr, *wihh = nullptr, *wihl = nullptr;
  if (planes) {
    whhh = (u16*)alloc((size_t)3072 * 1024 * 2);
    whhl = (u16*)alloc((size_t)3072 * 1024 * 2);
    wihh = (u16*)alloc((size_t)3072 * 256 * 2);
    wihl = (u16*)alloc((size_t)3072 * 256 * 2);
  }

  tsplit_k<<<dim3(512 / 32, 1024 / 32), 256, 0, stream>>>(w1, w1h, w1l, 512, 1024);
  tsplit_k<<<dim3(1024 / 32, 512 / 32), 256, 0, stream>>>(w2, w2h, w2l, 1024, 512);
  if (planes) {
    esplit_k<<<dim3((3072 * 1024) / 1024), 256, 0, stream>>>(whh, whhh, whhl);
    esplit_k<<<dim3((3072 * 256) / 1024), 256, 0, stream>>>(wih, wihh, wihl);
  }
  init_k<<<dim3(256), 256, 0, stream>>>(c0h, c0l, bar);

  if (planes) {
    fused_seq_k<true><<<dim3(NBLK), dim3(256), 0, stream>>>(
        w1h, w1l, w2h, w2l, b1, b2, c0h, c0l, c1h, c1l, h1h, h1l,
        whh, whhh, whhl, wih, wihh, wihl, bih, bhh, data, out, bar);
  } else {
    fused_seq_k<false><<<dim3(NBLK), dim3(256), 0, stream>>>(
        w1h, w1l, w2h, w2l, b1, b2, c0h, c0l, c1h, c1l, h1h, h1l,
        whh, whhh, whhl, wih, wihh, wihl, bih, bhh, data, out, bar);
  }
}